// Round 2
// baseline (40.858 us; speedup 1.0000x reference)
//
#include <hip/hip_runtime.h>
#include <stdint.h>

#define BATCH 128
#define NELEM 33600
#define HALF  16800          // elements per half-row block
#define NCH   6
#define TOPK  300
#define NT1   1024
#define PT    17             // ceil(16800/1024)
#define CAP2  448            // per-half-row candidate capacity (expect ~305)
#define NT2   1024

__device__ __forceinline__ uint32_t fkey(float f) {
    uint32_t u = __float_as_uint(f);
    // order-preserving: descending float == descending unsigned key
    return (u & 0x80000000u) ? ~u : (u | 0x80000000u);
}

// ---------------- kernel 1: per half-row local top-(>=300) candidates ----
__global__ __launch_bounds__(NT1) void k1_select(
    const float* __restrict__ preds, uint64_t* __restrict__ cand_g,
    uint32_t* __restrict__ cnt_g)
{
    const int blk  = blockIdx.x;      // 0..255
    const int b    = blk >> 1;
    const int seg  = blk & 1;
    const int tid  = threadIdx.x;
    const int wave = tid >> 6;
    const float* row = preds + (size_t)b * (NELEM * NCH);
    const int base_i = seg * HALF;

    __shared__ uint32_t hist[16][256];   // [wave][bin] -> bin%32 banks, conflict-free merge
    __shared__ uint32_t suf[256];
    __shared__ uint32_t h2[256];
    __shared__ uint32_t sh_b1, sh_S1, sh_thr, ccount;

    for (int i = tid; i < 16 * 256; i += NT1) ((uint32_t*)hist)[i] = 0;
    if (tid == 0) ccount = 0;
    __syncthreads();

    // ---- load scores -> order-preserving keys in regs + MSB histogram ----
    uint32_t key[PT];
    #pragma unroll
    for (int j = 0; j < PT; ++j) {
        int li = tid + j * NT1;
        if (li < HALF) {
            float s = row[(size_t)(base_i + li) * NCH + 4];
            uint32_t k = fkey(s);
            key[j] = k;
            atomicAdd(&hist[wave][k >> 24], 1u);
        } else key[j] = 0u;
    }
    __syncthreads();

    // ---- merge per-wave histograms ----
    if (tid < 256) {
        uint32_t s = 0;
        #pragma unroll
        for (int w = 0; w < 16; ++w) s += hist[w][tid];
        suf[tid] = s;
    }
    __syncthreads();

    // ---- suffix scan: suf[t] = count(bin >= t) ----
    for (int d = 1; d < 256; d <<= 1) {
        uint32_t t = 0;
        if (tid < 256 && tid + d < 256) t = suf[tid + d];
        __syncthreads();
        if (tid < 256) suf[tid] += t;
        __syncthreads();
    }
    if (tid < 256) {
        uint32_t hi = (tid == 255) ? 0u : suf[tid + 1];
        if (suf[tid] >= TOPK && hi < TOPK) { sh_b1 = (uint32_t)tid; sh_S1 = hi; }
        h2[tid] = 0;
    }
    __syncthreads();
    const uint32_t b1 = sh_b1, S1 = sh_S1;

    // ---- refine within bin b1 over key bits [23:16] ----
    #pragma unroll
    for (int j = 0; j < PT; ++j) {
        int li = tid + j * NT1;
        if (li < HALF && (key[j] >> 24) == b1)
            atomicAdd(&h2[(key[j] >> 16) & 0xFFu], 1u);
    }
    __syncthreads();
    for (int d = 1; d < 256; d <<= 1) {
        uint32_t t = 0;
        if (tid < 256 && tid + d < 256) t = h2[tid + d];
        __syncthreads();
        if (tid < 256) h2[tid] += t;
        __syncthreads();
    }
    if (tid < 256) {
        uint32_t hi = (tid == 255) ? 0u : h2[tid + 1];
        if (S1 + h2[tid] >= TOPK && S1 + hi < TOPK)
            sh_thr = (b1 << 8) | (uint32_t)tid;
    }
    __syncthreads();
    const uint32_t thr = sh_thr;

    // ---- emit candidates (16-bit prefix >= thr): ~302-310 per half ----
    uint64_t* cbase = cand_g + (size_t)blk * CAP2;
    #pragma unroll
    for (int j = 0; j < PT; ++j) {
        int li = tid + j * NT1;
        if (li < HALF && (key[j] >> 16) >= thr) {
            uint32_t pos = atomicAdd(&ccount, 1u);
            if (pos < CAP2)
                cbase[pos] = ((uint64_t)key[j] << 32)
                           | (uint32_t)(~(uint32_t)(base_i + li));
        }
    }
    __syncthreads();
    if (tid == 0) cnt_g[blk] = min(ccount, (uint32_t)CAP2);
}

// ---------------- kernel 2: merge halves, exact rank, gather + transform ----
__global__ __launch_bounds__(NT2) void k2_rank(
    const float* __restrict__ preds, const uint64_t* __restrict__ cand_g,
    const uint32_t* __restrict__ cnt_g, float* __restrict__ out)
{
    const int b   = blockIdx.x;
    const int tid = threadIdx.x;

    __shared__ uint64_t cand[2 * CAP2];
    __shared__ uint32_t c0s, c1s;

    if (tid == 0) { c0s = cnt_g[2 * b]; c1s = cnt_g[2 * b + 1]; }
    __syncthreads();
    const int c0 = (int)c0s, c1 = (int)c1s;
    const int Cn = c0 + c1;                       // <= 896 <= NT2

    if (tid < c0)            cand[tid] = cand_g[(size_t)(2 * b) * CAP2 + tid];
    else if (tid - c0 < c1)  cand[tid] = cand_g[(size_t)(2 * b + 1) * CAP2 + (tid - c0)];
    __syncthreads();

    if (tid < Cn) {
        const uint64_t mine = cand[tid];
        int rank = 0;
        for (int j = 0; j < Cn; ++j) rank += (cand[j] > mine) ? 1 : 0;
        if (rank < TOPK) {
            uint32_t idx = ~(uint32_t)(mine & 0xFFFFFFFFu);
            const float* e = preds + (size_t)b * (NELEM * NCH) + (size_t)idx * NCH;
            float p0 = e[0], p1 = e[1], p2 = e[2], p3 = e[3], p4 = e[4], p5 = e[5];
            const float inv = 1.0f / 1280.0f;
            float x1 = p0 * inv, y1 = p1 * inv, x2 = p2 * inv, y2 = p3 * inv;
            float* o = out + (size_t)b * (TOPK * NCH) + (size_t)rank * NCH;
            o[0] = (x1 + x2) * 0.5f;
            o[1] = (y1 + y2) * 0.5f;
            o[2] = x2 - x1;
            o[3] = y2 - y1;
            o[4] = p4;
            o[5] = p5;
        }
    }
}

extern "C" void kernel_launch(void* const* d_in, const int* in_sizes, int n_in,
                              void* d_out, int out_size, void* d_ws, size_t ws_size,
                              hipStream_t stream) {
    const float* preds = (const float*)d_in[0];
    float* out = (float*)d_out;

    // workspace layout: candidates (256*CAP2 u64) then counts (256 u32)
    uint64_t* cand_g = (uint64_t*)d_ws;
    uint32_t* cnt_g  = (uint32_t*)((char*)d_ws + (size_t)2 * BATCH * CAP2 * sizeof(uint64_t));

    hipLaunchKernelGGL(k1_select, dim3(2 * BATCH), dim3(NT1), 0, stream,
                       preds, cand_g, cnt_g);
    hipLaunchKernelGGL(k2_rank, dim3(BATCH), dim3(NT2), 0, stream,
                       preds, cand_g, cnt_g, out);
}

// Round 3
// 38.538 us; speedup vs baseline: 1.0602x; 1.0602x over previous
//
#include <hip/hip_runtime.h>
#include <stdint.h>

#define BATCH 128
#define NELEM 33600
#define HALF  16800          // elements per half-row block
#define NCH   6
#define TOPK  300
#define NT1   1024
#define PT    17             // ceil(16800/1024)
#define CAP2  448            // per-half-row candidate capacity (expect ~305)
#define NT2   1024

__device__ __forceinline__ uint32_t fkey(float f) {
    uint32_t u = __float_as_uint(f);
    // order-preserving: descending float == descending unsigned key
    return (u & 0x80000000u) ? ~u : (u | 0x80000000u);
}

// ---------------- kernel 1: per half-row local top-(>=300) candidates ----
__global__ __launch_bounds__(NT1) void k1_select(
    const float* __restrict__ preds, uint64_t* __restrict__ cand_g,
    uint32_t* __restrict__ cnt_g)
{
    const int blk  = blockIdx.x;      // 0..255
    const int b    = blk >> 1;
    const int seg  = blk & 1;
    const int tid  = threadIdx.x;
    const int wave = tid >> 6;
    const float* row = preds + (size_t)b * (NELEM * NCH);
    const int base_i = seg * HALF;

    __shared__ uint32_t hist[16][256];   // [wave][bin] -> bank=bin%32, spread
    __shared__ uint32_t suf[256];
    __shared__ uint32_t h2[256];
    __shared__ uint32_t sh_b1, sh_S1, sh_thr, ccount;

    for (int i = tid; i < 16 * 256; i += NT1) ((uint32_t*)hist)[i] = 0;
    if (tid == 0) ccount = 0;
    __syncthreads();

    // ---- load scores -> order-preserving keys in regs + MSB histogram ----
    uint32_t key[PT];
    #pragma unroll
    for (int j = 0; j < PT; ++j) {
        int li = tid + j * NT1;
        if (li < HALF) {
            float s = row[(size_t)(base_i + li) * NCH + 4];
            uint32_t k = fkey(s);
            key[j] = k;
            atomicAdd(&hist[wave][k >> 24], 1u);
        } else key[j] = 0u;
    }
    __syncthreads();

    // ---- merge per-wave histograms ----
    if (tid < 256) {
        uint32_t s = 0;
        #pragma unroll
        for (int w = 0; w < 16; ++w) s += hist[w][tid];
        suf[tid] = s;
    }
    __syncthreads();

    // ---- suffix scan: suf[t] = count(bin >= t) ----
    for (int d = 1; d < 256; d <<= 1) {
        uint32_t t = 0;
        if (tid < 256 && tid + d < 256) t = suf[tid + d];
        __syncthreads();
        if (tid < 256) suf[tid] += t;
        __syncthreads();
    }
    if (tid < 256) {
        uint32_t hi = (tid == 255) ? 0u : suf[tid + 1];
        if (suf[tid] >= TOPK && hi < TOPK) { sh_b1 = (uint32_t)tid; sh_S1 = hi; }
        h2[tid] = 0;
    }
    __syncthreads();
    const uint32_t b1 = sh_b1, S1 = sh_S1;

    // ---- refine within bin b1 over key bits [23:16] ----
    #pragma unroll
    for (int j = 0; j < PT; ++j) {
        int li = tid + j * NT1;
        if (li < HALF && (key[j] >> 24) == b1)
            atomicAdd(&h2[(key[j] >> 16) & 0xFFu], 1u);
    }
    __syncthreads();
    for (int d = 1; d < 256; d <<= 1) {
        uint32_t t = 0;
        if (tid < 256 && tid + d < 256) t = h2[tid + d];
        __syncthreads();
        if (tid < 256) h2[tid] += t;
        __syncthreads();
    }
    if (tid < 256) {
        uint32_t hi = (tid == 255) ? 0u : h2[tid + 1];
        if (S1 + h2[tid] >= TOPK && S1 + hi < TOPK)
            sh_thr = (b1 << 8) | (uint32_t)tid;
    }
    __syncthreads();
    const uint32_t thr = sh_thr;

    // ---- emit candidates (16-bit prefix >= thr): ~302-320 per half ----
    uint64_t* cbase = cand_g + (size_t)blk * CAP2;
    #pragma unroll
    for (int j = 0; j < PT; ++j) {
        int li = tid + j * NT1;
        if (li < HALF && (key[j] >> 16) >= thr) {
            uint32_t pos = atomicAdd(&ccount, 1u);
            if (pos < CAP2)
                cbase[pos] = ((uint64_t)key[j] << 32)
                           | (uint32_t)(~(uint32_t)(base_i + li));
        }
    }
    __syncthreads();
    if (tid == 0) cnt_g[blk] = min(ccount, (uint32_t)CAP2);
}

// ---------------- kernel 2: merge halves, exact rank, gather + transform ----
__global__ __launch_bounds__(NT2) void k2_rank(
    const float* __restrict__ preds, const uint64_t* __restrict__ cand_g,
    const uint32_t* __restrict__ cnt_g, float* __restrict__ out)
{
    const int b   = blockIdx.x;
    const int tid = threadIdx.x;

    __shared__ uint64_t cand[2 * CAP2];
    __shared__ uint32_t c0s, c1s;

    if (tid == 0) { c0s = cnt_g[2 * b]; c1s = cnt_g[2 * b + 1]; }
    __syncthreads();
    const int c0 = (int)c0s, c1 = (int)c1s;
    const int Cn = c0 + c1;                       // <= 896 <= NT2

    if (tid < c0)            cand[tid] = cand_g[(size_t)(2 * b) * CAP2 + tid];
    else if (tid - c0 < c1)  cand[tid] = cand_g[(size_t)(2 * b + 1) * CAP2 + (tid - c0)];
    __syncthreads();

    if (tid < Cn) {
        const uint64_t mine = cand[tid];
        int rank = 0;
        // hand-unrolled x16: 16 independent ds_read_b64 in flight per batch
        // (breaks the per-iteration ds_read->waitcnt serial latency chain)
        int j = 0;
        for (; j + 16 <= Cn; j += 16) {
            #pragma unroll
            for (int u = 0; u < 16; ++u)
                rank += (cand[j + u] > mine) ? 1 : 0;
        }
        for (; j < Cn; ++j) rank += (cand[j] > mine) ? 1 : 0;

        if (rank < TOPK) {
            uint32_t idx = ~(uint32_t)(mine & 0xFFFFFFFFu);
            const float* e = preds + (size_t)b * (NELEM * NCH) + (size_t)idx * NCH;
            float p0 = e[0], p1 = e[1], p2 = e[2], p3 = e[3], p4 = e[4], p5 = e[5];
            const float inv = 1.0f / 1280.0f;
            float x1 = p0 * inv, y1 = p1 * inv, x2 = p2 * inv, y2 = p3 * inv;
            float* o = out + (size_t)b * (TOPK * NCH) + (size_t)rank * NCH;
            o[0] = (x1 + x2) * 0.5f;
            o[1] = (y1 + y2) * 0.5f;
            o[2] = x2 - x1;
            o[3] = y2 - y1;
            o[4] = p4;
            o[5] = p5;
        }
    }
}

extern "C" void kernel_launch(void* const* d_in, const int* in_sizes, int n_in,
                              void* d_out, int out_size, void* d_ws, size_t ws_size,
                              hipStream_t stream) {
    const float* preds = (const float*)d_in[0];
    float* out = (float*)d_out;

    // workspace layout: candidates (256*CAP2 u64) then counts (256 u32)
    uint64_t* cand_g = (uint64_t*)d_ws;
    uint32_t* cnt_g  = (uint32_t*)((char*)d_ws + (size_t)2 * BATCH * CAP2 * sizeof(uint64_t));

    hipLaunchKernelGGL(k1_select, dim3(2 * BATCH), dim3(NT1), 0, stream,
                       preds, cand_g, cnt_g);
    hipLaunchKernelGGL(k2_rank, dim3(BATCH), dim3(NT2), 0, stream,
                       preds, cand_g, cnt_g, out);
}

// Round 4
// 33.854 us; speedup vs baseline: 1.2069x; 1.1383x over previous
//
#include <hip/hip_runtime.h>
#include <stdint.h>

#define BATCH 128
#define NELEM 33600
#define HALF  16800
#define NCH   6
#define TOPK  300
#define NT1   1024
#define PT    17             // ceil(16800/1024)
#define CAP2  448            // per-half-row candidate capacity (expect ~305)
#define NT2   1024

__device__ __forceinline__ uint32_t fkey(float f) {
    uint32_t u = __float_as_uint(f);
    // order-preserving: descending float == descending unsigned key
    return (u & 0x80000000u) ? ~u : (u | 0x80000000u);
}

// ---- kernel 1: per half-row candidates, exact local sort, emit top-300 ----
__global__ __launch_bounds__(NT1) void k1_select(
    const float* __restrict__ preds, uint64_t* __restrict__ sorted_g)
{
    const int blk  = blockIdx.x;      // 0..255
    const int b    = blk >> 1;
    const int seg  = blk & 1;
    const int tid  = threadIdx.x;
    const int lane = tid & 63;
    const int wave = tid >> 6;
    const float* row = preds + (size_t)b * (NELEM * NCH);
    const int base_i = seg * HALF;

    __shared__ uint32_t hist[16][257];   // +1 pad: bank=(wave+bin)%32, hot bins spread
    __shared__ uint32_t suf[256];
    __shared__ uint32_t h2[256];
    __shared__ __align__(16) uint64_t cand[CAP2 + 4];
    __shared__ uint32_t sh_b1, sh_S1, sh_thr, ccount;

    for (int i = tid; i < 16 * 257; i += NT1) ((uint32_t*)hist)[i] = 0;
    if (tid == 0) ccount = 0;
    __syncthreads();

    // ---- load scores -> order-preserving keys in regs + MSB histogram ----
    uint32_t key[PT];
    #pragma unroll
    for (int j = 0; j < PT; ++j) {
        int li = tid + j * NT1;
        if (li < HALF) {
            float s = row[(size_t)(base_i + li) * NCH + 4];
            uint32_t k = fkey(s);
            key[j] = k;
            atomicAdd(&hist[wave][k >> 24], 1u);
        } else key[j] = 0u;
    }
    __syncthreads();

    // ---- merge per-wave histograms ----
    if (tid < 256) {
        uint32_t s = 0;
        #pragma unroll
        for (int w = 0; w < 16; ++w) s += hist[w][tid];
        suf[tid] = s;
    }
    __syncthreads();

    // ---- suffix scan: suf[t] = count(bin >= t) ----
    for (int d = 1; d < 256; d <<= 1) {
        uint32_t t = 0;
        if (tid < 256 && tid + d < 256) t = suf[tid + d];
        __syncthreads();
        if (tid < 256) suf[tid] += t;
        __syncthreads();
    }
    if (tid < 256) {
        uint32_t hi = (tid == 255) ? 0u : suf[tid + 1];
        if (suf[tid] >= TOPK && hi < TOPK) { sh_b1 = (uint32_t)tid; sh_S1 = hi; }
        h2[tid] = 0;
    }
    __syncthreads();
    const uint32_t b1 = sh_b1, S1 = sh_S1;

    // ---- refine within bin b1 over key bits [23:16] (~400 elements) ----
    #pragma unroll
    for (int j = 0; j < PT; ++j) {
        int li = tid + j * NT1;
        if (li < HALF && (key[j] >> 24) == b1)
            atomicAdd(&h2[(key[j] >> 16) & 0xFFu], 1u);
    }
    __syncthreads();
    for (int d = 1; d < 256; d <<= 1) {
        uint32_t t = 0;
        if (tid < 256 && tid + d < 256) t = h2[tid + d];
        __syncthreads();
        if (tid < 256) h2[tid] += t;
        __syncthreads();
    }
    if (tid < 256) {
        uint32_t hi = (tid == 255) ? 0u : h2[tid + 1];
        if (S1 + h2[tid] >= TOPK && S1 + hi < TOPK)
            sh_thr = (b1 << 8) | (uint32_t)tid;
    }
    __syncthreads();
    const uint32_t thr = sh_thr;

    // ---- collect candidates to LDS (wave-aggregated atomic) ----
    #pragma unroll
    for (int j = 0; j < PT; ++j) {
        int li = tid + j * NT1;
        bool pred = (li < HALF) && ((key[j] >> 16) >= thr);
        uint64_t m = __ballot(pred);
        if (m) {
            int leader = (int)__ffsll((long long)m) - 1;
            uint32_t base;
            if (lane == leader) base = atomicAdd(&ccount, (uint32_t)__popcll(m));
            base = __shfl(base, leader);
            if (pred) {
                uint32_t pos = base + (uint32_t)__popcll(m & ((1ull << lane) - 1ull));
                if (pos < CAP2)
                    cand[pos] = ((uint64_t)key[j] << 32)
                              | (uint32_t)(~(uint32_t)(base_i + li));
            }
        }
    }
    __syncthreads();
    const int Cn = (int)min(ccount, (uint32_t)CAP2);
    if (tid < 4) cand[Cn + tid] = 0ull;          // pad for paired reads
    __syncthreads();

    // ---- exact local rank (desc key, asc idx) via b128 broadcast reads ----
    if (tid < Cn) {
        const uint64_t mine = cand[tid];
        int rank = 0;
        const ulonglong2* c2 = (const ulonglong2*)cand;
        const int npair = (Cn + 1) >> 1;
        int p = 0;
        for (; p + 8 <= npair; p += 8) {
            #pragma unroll
            for (int u = 0; u < 8; ++u) {
                ulonglong2 v = c2[p + u];
                rank += (v.x > mine) ? 1 : 0;
                rank += (v.y > mine) ? 1 : 0;
            }
        }
        for (; p < npair; ++p) {
            ulonglong2 v = c2[p];
            rank += (v.x > mine) ? 1 : 0;
            rank += (v.y > mine) ? 1 : 0;
        }
        if (rank < TOPK)
            sorted_g[(size_t)blk * TOPK + rank] = mine;   // all 300 slots filled
    }
}

// ---- kernel 2: merge two sorted 300-lists by binary search, emit boxes ----
__global__ __launch_bounds__(NT2) void k2_merge(
    const float* __restrict__ preds, const uint64_t* __restrict__ sorted_g,
    float* __restrict__ out)
{
    const int b   = blockIdx.x;
    const int tid = threadIdx.x;

    __shared__ uint64_t sA[TOPK], sB[TOPK];
    if (tid < TOPK)
        sA[tid] = sorted_g[(size_t)(2 * b) * TOPK + tid];
    else if (tid >= 512 && tid < 512 + TOPK)
        sB[tid - 512] = sorted_g[(size_t)(2 * b + 1) * TOPK + (tid - 512)];
    __syncthreads();

    int i = -1; uint64_t mine = 0; const uint64_t* other = sA;
    if (tid < TOPK)                         { i = tid;       mine = sA[i]; other = sB; }
    else if (tid >= 512 && tid < 512 + TOPK){ i = tid - 512; mine = sB[i]; other = sA; }

    if (i >= 0) {
        // count of elements in `other` strictly greater than mine (desc sorted)
        int lo = 0, hi = TOPK;
        while (lo < hi) {
            int mid = (lo + hi) >> 1;
            if (other[mid] > mine) lo = mid + 1; else hi = mid;
        }
        int rank = i + lo;
        if (rank < TOPK) {
            uint32_t idx = ~(uint32_t)(mine & 0xFFFFFFFFu);
            const float* e = preds + (size_t)b * (NELEM * NCH) + (size_t)idx * NCH;
            float p0 = e[0], p1 = e[1], p2 = e[2], p3 = e[3], p4 = e[4], p5 = e[5];
            const float inv = 1.0f / 1280.0f;
            float x1 = p0 * inv, y1 = p1 * inv, x2 = p2 * inv, y2 = p3 * inv;
            float* o = out + (size_t)b * (TOPK * NCH) + (size_t)rank * NCH;
            o[0] = (x1 + x2) * 0.5f;
            o[1] = (y1 + y2) * 0.5f;
            o[2] = x2 - x1;
            o[3] = y2 - y1;
            o[4] = p4;
            o[5] = p5;
        }
    }
}

extern "C" void kernel_launch(void* const* d_in, const int* in_sizes, int n_in,
                              void* d_out, int out_size, void* d_ws, size_t ws_size,
                              hipStream_t stream) {
    const float* preds = (const float*)d_in[0];
    float* out = (float*)d_out;
    uint64_t* sorted_g = (uint64_t*)d_ws;   // 256 * 300 * 8 B = 600 KiB

    hipLaunchKernelGGL(k1_select, dim3(2 * BATCH), dim3(NT1), 0, stream,
                       preds, sorted_g);
    hipLaunchKernelGGL(k2_merge, dim3(BATCH), dim3(NT2), 0, stream,
                       preds, sorted_g, out);
}